// Round 11
// baseline (7651.530 us; speedup 1.0000x reference)
//
#include <hip/hip_runtime.h>

typedef _Float16 f16;
typedef _Float16 f16x8 __attribute__((ext_vector_type(8)));
typedef float f32x4 __attribute__((ext_vector_type(4)));
typedef unsigned int u32;
typedef unsigned long long u64;
typedef u32 u32x4 __attribute__((ext_vector_type(4)));

#define SEQ 2048
#define NBAT 64
#define NH 512
#define OUT0_ELEMS (SEQ * NBAT * NH)
#define TSLICE (NBAT * NH)  // 32768 f32 per t-slice (131072 B)

#define AGENT __HIP_MEMORY_SCOPE_AGENT
#define RLX __ATOMIC_RELAXED

// ws layout (memset [0,8192) each launch; rings are flag-gated, not cleared):
//   [0,64)        gab
//   64+c*512      tags0[32] (4B stride) @+0, tags1[32] @+128   (c = 0..3)
//   8192          ring0: + c*262144, 16 slots x 16384B ([16 b][512 f] f16)
//   1056768       ring1: + c*32768,   2 slots x 16384B
#define WS_FLAGS 64
#define WS_RING0 8192
#define WS_RING1 (8192 + 4 * 262144)

#define MFMA16(a, b, c) __builtin_amdgcn_mfma_f32_16x16x32_f16((a), (b), (c), 0, 0, 0)

#define WAIT_VM0()                                   \
  do {                                               \
    asm volatile("s_waitcnt vmcnt(0)" ::: "memory"); \
    __builtin_amdgcn_sched_barrier(0);               \
  } while (0)

// ---- agent-scope (R1/R4/R6/R8/R10-proven) memory ops: sc0 sc1 ----
__device__ __forceinline__ u32x4 ld_sc(const void* p) {
  u32x4 d;
  asm volatile("global_load_dwordx4 %0, %1, off sc0 sc1" : "=v"(d) : "v"(p) : "memory");
  return d;
}
__device__ __forceinline__ void st_sc_u32(void* p, u32 v) {
  asm volatile("global_store_dword %0, %1, off sc0 sc1" ::"v"(p), "v"(v) : "memory");
}
__device__ __forceinline__ void st_sc_u16(void* p, u32 v) {
  asm volatile("global_store_short %0, %1, off sc0 sc1" ::"v"(p), "v"(v) : "memory");
}
__device__ __forceinline__ u32 poll_sc(const void* p) {
  u32 d;
  asm volatile("global_load_dword %0, %1, off sc0 sc1\n\ts_waitcnt vmcnt(0)"
               : "=v"(d) : "v"(p) : "memory");
  return d;
}

__device__ __forceinline__ f16x8 cvt2(float4 a, float4 b) {
  f16x8 v;
  v[0] = (f16)a.x; v[1] = (f16)a.y; v[2] = (f16)a.z; v[3] = (f16)a.w;
  v[4] = (f16)b.x; v[5] = (f16)b.y; v[6] = (f16)b.z; v[7] = (f16)b.w;
  return v;
}
__device__ __forceinline__ f16x8 ldcvt8(const float* p) {
  float4 a = *(const float4*)p;
  float4 b = *(const float4*)(p + 4);
  return cvt2(a, b);
}
__device__ __forceinline__ u32 h2b(float v) {
  union { f16 h[2]; u32 u; } x;
  x.u = 0;
  x.h[0] = (f16)v;
  return x.u;
}
__device__ __forceinline__ f32x4 cvt4(u64 q) {
  union { u64 q; f16 h[4]; } u;
  u.q = q;
  f32x4 r;
  r[0] = (float)u.h[0]; r[1] = (float)u.h[1];
  r[2] = (float)u.h[2]; r[3] = (float)u.h[3];
  return r;
}

// lanes<32 poll tags0[lane] >= tgtA ; lanes>=32 poll tags1[lane-32] >= tgtB
// (tags packed at 4B stride: tags0 @ fb+0..128, tags1 @ fb+128..256)
__device__ __forceinline__ bool spin2(const char* fb, u32 tgtA, u32 tgtB, u32* gab) {
  const int lane = threadIdx.x & 63;
  const char* p = fb + lane * 4;
  const u32 tgt = (lane < 32) ? tgtA : tgtB;
  int it = 0;
  for (;;) {
    u32 v = poll_sc(p);
    if (__all((int)(v >= tgt))) return true;
    if (((++it) & 63) == 0) {
      if (__hip_atomic_load(gab, RLX, AGENT) || it > (1 << 20)) {
        __hip_atomic_store(gab, 1u, RLX, AGENT);
        return false;
      }
    }
  }
}

// ====== kernel 1: pre0[t] = b_ih0 + b_hh0 + Wi0 @ x[t], f16 D-frag layout ======
// No LDS: each wave loads its A-frags directly (L2 absorbs the 4x wave reuse).
// Output f16x4 per lane-slot, packed in the first 64KB of each out t-slice.
// grid 2048 = c(4) x r(8) x ch(64); block 256.
__global__ __launch_bounds__(256) void pre0_gemm(
    const float* __restrict__ x, const float* __restrict__ w_ih,
    const float* __restrict__ b_ih, const float* __restrict__ b_hh,
    float* __restrict__ out) {
  const int tid = threadIdx.x;
  const int lane = tid & 63;
  const int wv = tid >> 6;
  const int bid = blockIdx.x;
  const int c = bid >> 9;
  const int r = (bid >> 6) & 7;
  const int ch = bid & 63;
  const int gb = c * 16;
  const int mrow = lane & 15;
  const int kgrp = lane >> 4;
  const int jl = wv * 16 + mrow;
  const int jg = r * 64 + jl;

  f16x8 wif[16];
  {
    const float* s1 = w_ih + (size_t)jg * NH + kgrp * 8;
#pragma unroll
    for (int kk = 0; kk < 16; ++kk) wif[kk] = ldcvt8(s1 + kk * 32);
  }
  const float bias = b_ih[jg] + b_hh[jg];
  const f32x4 bias4 = {bias, bias, bias, bias};
  const f32x4 zero4 = {0.f, 0.f, 0.f, 0.f};

  unsigned short* oh = (unsigned short*)out;
  const int fi = ((c * 8 + r) * 4 + wv) * 64 + kgrp * 16 + mrow;

  for (int ti = 0; ti < 32; ++ti) {
    const int t = ch * 32 + ti;
    const float* xb = x + ((size_t)t * NBAT + gb + mrow) * NH + kgrp * 8;
    f32x4 c0 = bias4, c1 = zero4, c2 = zero4, c3 = zero4;
#pragma unroll
    for (int kk = 0; kk < 16; kk += 4) {
      c0 = MFMA16(ldcvt8(xb + (kk + 0) * 32), wif[kk + 0], c0);
      c1 = MFMA16(ldcvt8(xb + (kk + 1) * 32), wif[kk + 1], c1);
      c2 = MFMA16(ldcvt8(xb + (kk + 2) * 32), wif[kk + 2], c2);
      c3 = MFMA16(ldcvt8(xb + (kk + 3) * 32), wif[kk + 3], c3);
    }
    f32x4 acc = (c0 + c1) + (c2 + c3);
    union { f16 h[4]; u64 q; } pk;
    pk.h[0] = (f16)acc[0]; pk.h[1] = (f16)acc[1];
    pk.h[2] = (f16)acc[2]; pk.h[3] = (f16)acc[3];
    *(u64*)(oh + (size_t)t * 65536 + (size_t)fi * 4) = pk.q;
  }
}

// ===== kernel 2: persistent recurrence (R10 template; 16-slot ring0, f16 pre0) =
// grid = 64 WGs x 256 thr. c = bid>>4 (16 batches), layer = (bid>>3)&1, r = bid&7.
__global__ __launch_bounds__(256, 1) void rnn_pers(
    const float* __restrict__ x, const float* __restrict__ hx,
    const float* __restrict__ w_ih, const float* __restrict__ w_hh,
    const float* __restrict__ b_ih, const float* __restrict__ b_hh,
    float* __restrict__ out, char* __restrict__ ws) {
  __shared__ __align__(16) char SA[16384];
  __shared__ __align__(16) char SB[16384];
  __shared__ u32 okf;

  const int tid = threadIdx.x;
  const int lane = tid & 63;
  const int wv = tid >> 6;
  const int bid = blockIdx.x;
  const int c = bid >> 4;
  const int layer = (bid >> 3) & 1;
  const int r = bid & 7;

  const int mrow = lane & 15;     // A-row = batch 0..15 (all real)
  const int kgrp = lane >> 4;     // 0..3
  const int jl = wv * 16 + mrow;  // feature within 64-slice
  const int jg = r * 64 + jl;     // global feature
  const int gb = c * 16;
  const int fq4 = (r * 4 + wv) * 4;
  const int rsw = (mrow & 7) << 4;

  // cooperative staging geometry: thread stages 64B of the 16KB slot:
  // src bytes tid*64 .. +63 ; LDS row ro=tid>>4, cols ((tid&15)*64+j*16)^((ro&7)<<4)
  const int q64 = tid * 64;
  const int ro = tid >> 4;
  const int wb = ro * 1024;
  const int wsw = (ro & 7) << 4;
  const int wc0 = wb + ((((tid & 15) * 64) + 0) ^ wsw);
  const int wc1 = wb + ((((tid & 15) * 64) + 16) ^ wsw);
  const int wc2 = wb + ((((tid & 15) * 64) + 32) ^ wsw);
  const int wc3 = wb + ((((tid & 15) * 64) + 48) ^ wsw);

  u32* gab = (u32*)ws;
  char* fb = ws + WS_FLAGS + c * 512;
  char* ring0 = ws + WS_RING0 + (size_t)c * 262144;  // 16 slots
  char* ring1 = ws + WS_RING1 + (size_t)c * 32768;   // 2 slots

  // wv0 polls; okf broadcasts; abort returns the WHOLE WG together (barrier-safe)
#define SPIN_OR_DIE(tgA, tgB)                  \
  do {                                         \
    if (wv == 0) {                             \
      bool ok_ = spin2(fb, (tgA), (tgB), gab); \
      if (lane == 0) okf = ok_ ? 1u : 2u;      \
    }                                          \
    __syncthreads();                           \
    if (okf != 1u) return;                     \
  } while (0)

#define LA(kk) (*(const f16x8*)(SA + mrow * 1024 + ((kgrp * 16 + (kk) * 64) ^ rsw)))
#define LB(kk) (*(const f16x8*)(SB + mrow * 1024 + ((kgrp * 16 + (kk) * 64) ^ rsw)))

  f16x8 whf[16];
  {
    const float* s2 = w_hh + ((size_t)layer * NH + jg) * NH + kgrp * 8;
#pragma unroll
    for (int kk = 0; kk < 16; ++kk) whf[kk] = ldcvt8(s2 + kk * 32);
  }
  const f32x4 zero4 = {0.f, 0.f, 0.f, 0.f};

  if (layer == 0) {
    // ============================ LAYER 0 ============================
    const unsigned short* ph =
        (const unsigned short*)out +
        (size_t)(((c * 8 + r) * 4 + wv) * 64 + kgrp * 16 + mrow) * 4;
#define PRE(tt) (*(const u64*)(ph + (size_t)(tt) * 65536))
    u64 xpA = PRE(0);
    u64 xpB = PRE(1);
    u64 xpC = PRE(2);
    for (int t = 0; t < SEQ; ++t) {
      f32x4 c0 = cvt4(xpA), c1 = zero4, c2 = zero4, c3 = zero4;
      if (t == 0) {
        const float* hb = hx + (size_t)(gb + mrow) * NH + kgrp * 8;
#pragma unroll
        for (int kk = 0; kk < 16; kk += 4) {
          c0 = MFMA16(ldcvt8(hb + (kk + 0) * 32), whf[kk + 0], c0);
          c1 = MFMA16(ldcvt8(hb + (kk + 1) * 32), whf[kk + 1], c1);
          c2 = MFMA16(ldcvt8(hb + (kk + 2) * 32), whf[kk + 2], c2);
          c3 = MFMA16(ldcvt8(hb + (kk + 3) * 32), whf[kk + 3], c3);
        }
      } else {
        // tags0>=t : h0[t-1] ready ; tags1>=t-15 : ring0 slot t&15 reusable
        SPIN_OR_DIE((u32)t, (t >= 15) ? (u32)(t - 15) : 0u);
        {  // cooperative stage: ring0 slot (t-1)&15 -> SA (16KB once per WG)
          const char* sp = ring0 + (size_t)((t - 1) & 15) * 16384 + q64;
          u32x4 s0 = ld_sc(sp);
          u32x4 s1 = ld_sc(sp + 16);
          u32x4 s2 = ld_sc(sp + 32);
          u32x4 s3 = ld_sc(sp + 48);
          WAIT_VM0();  // asm loads MUST drain before LDS writes
          *(u32x4*)(SA + wc0) = s0;
          *(u32x4*)(SA + wc1) = s1;
          *(u32x4*)(SA + wc2) = s2;
          *(u32x4*)(SA + wc3) = s3;
        }
        __syncthreads();
#pragma unroll
        for (int kk = 0; kk < 16; kk += 4) {
          c0 = MFMA16(LA(kk + 0), whf[kk + 0], c0);
          c1 = MFMA16(LA(kk + 1), whf[kk + 1], c1);
          c2 = MFMA16(LA(kk + 2), whf[kk + 2], c2);
          c3 = MFMA16(LA(kk + 3), whf[kk + 3], c3);
        }
      }
      f32x4 acc = (c0 + c1) + (c2 + c3);
      float hv0 = fmaxf(acc[0], 0.f), hv1 = fmaxf(acc[1], 0.f);
      float hv2 = fmaxf(acc[2], 0.f), hv3 = fmaxf(acc[3], 0.f);
      if (t == SEQ - 1) {  // h_final layer 0 (16 real batches)
        float* hfo = out + OUT0_ELEMS + (size_t)gb * NH + jg;
        hfo[(size_t)(4 * kgrp + 0) * NH] = hv0;
        hfo[(size_t)(4 * kgrp + 1) * NH] = hv1;
        hfo[(size_t)(4 * kgrp + 2) * NH] = hv2;
        hfo[(size_t)(4 * kgrp + 3) * NH] = hv3;
      }
      {  // h0[t] -> ring0 slot t&15 (batch 4*kgrp+i, feature jg)
        char* rb = ring0 + (size_t)(t & 15) * 16384 + jg * 2;
        st_sc_u16(rb + (4 * kgrp + 0) * 1024, h2b(hv0));
        st_sc_u16(rb + (4 * kgrp + 1) * 1024, h2b(hv1));
        st_sc_u16(rb + (4 * kgrp + 2) * 1024, h2b(hv2));
        st_sc_u16(rb + (4 * kgrp + 3) * 1024, h2b(hv3));
      }
      WAIT_VM0();
      if (lane == 0) st_sc_u32(fb + fq4, (u32)(t + 1));
      xpA = xpB;  // pre0[t+3] prefetch: issued here, drained by next staging wait
      xpB = xpC;
      if (t + 3 < SEQ) xpC = PRE(t + 3);
    }
#undef PRE
  } else {
    // ============================ LAYER 1 ============================
    f16x8 wif[16];
    {
      const float* s1 = w_ih + ((size_t)NH + jg) * NH + kgrp * 8;
#pragma unroll
      for (int kk = 0; kk < 16; ++kk) wif[kk] = ldcvt8(s1 + kk * 32);
    }
    const float bias = b_ih[NH + jg] + b_hh[NH + jg];
    const f32x4 bias4 = {bias, bias, bias, bias};
    f32x4 xc0, xc1, xc2, xc3;
    // prologue: xacc = bias + Wi1 @ h0[0]
    SPIN_OR_DIE(1u, 0u);
    {  // stage ring0 slot 0 -> SB
      const char* sp = ring0 + q64;
      u32x4 s0 = ld_sc(sp);
      u32x4 s1 = ld_sc(sp + 16);
      u32x4 s2 = ld_sc(sp + 32);
      u32x4 s3 = ld_sc(sp + 48);
      WAIT_VM0();
      *(u32x4*)(SB + wc0) = s0;
      *(u32x4*)(SB + wc1) = s1;
      *(u32x4*)(SB + wc2) = s2;
      *(u32x4*)(SB + wc3) = s3;
    }
    __syncthreads();
    xc0 = bias4; xc1 = zero4; xc2 = zero4; xc3 = zero4;
#pragma unroll
    for (int kk = 0; kk < 16; kk += 4) {
      xc0 = MFMA16(LB(kk + 0), wif[kk + 0], xc0);
      xc1 = MFMA16(LB(kk + 1), wif[kk + 1], xc1);
      xc2 = MFMA16(LB(kk + 2), wif[kk + 2], xc2);
      xc3 = MFMA16(LB(kk + 3), wif[kk + 3], xc3);
    }
    for (int t = 0; t < SEQ; ++t) {
      // tags0>=t+2 : h0[t+1] ready ; tags1>=t : h1[t-1] ready
      u32 tgtA = (t < SEQ - 1) ? (u32)(t + 2) : (u32)SEQ;
      SPIN_OR_DIE(tgtA, (u32)t);
      {  // cooperative stage: SA <- ring1 slot (t-1)&1 ; SB <- ring0 slot (t+1)&15
        u32x4 a0, a1, a2, a3, b0, b1, b2, b3;
        const bool doA = (t >= 1), doB = (t < SEQ - 1);
        if (doA) {
          const char* sp = ring1 + (size_t)((t - 1) & 1) * 16384 + q64;
          a0 = ld_sc(sp); a1 = ld_sc(sp + 16); a2 = ld_sc(sp + 32); a3 = ld_sc(sp + 48);
        }
        if (doB) {
          const char* sp = ring0 + (size_t)((t + 1) & 15) * 16384 + q64;
          b0 = ld_sc(sp); b1 = ld_sc(sp + 16); b2 = ld_sc(sp + 32); b3 = ld_sc(sp + 48);
        }
        WAIT_VM0();  // drain ALL asm loads before LDS writes
        if (doA) {
          *(u32x4*)(SA + wc0) = a0; *(u32x4*)(SA + wc1) = a1;
          *(u32x4*)(SA + wc2) = a2; *(u32x4*)(SA + wc3) = a3;
        }
        if (doB) {
          *(u32x4*)(SB + wc0) = b0; *(u32x4*)(SB + wc1) = b1;
          *(u32x4*)(SB + wc2) = b2; *(u32x4*)(SB + wc3) = b3;
        }
      }
      __syncthreads();
      f32x4 c0 = xc0, c1 = xc1, c2 = xc2, c3 = xc3;
      if (t == 0) {
        const float* hb = hx + (size_t)(NBAT + gb + mrow) * NH + kgrp * 8;
#pragma unroll
        for (int kk = 0; kk < 16; kk += 4) {
          c0 = MFMA16(ldcvt8(hb + (kk + 0) * 32), whf[kk + 0], c0);
          c1 = MFMA16(ldcvt8(hb + (kk + 1) * 32), whf[kk + 1], c1);
          c2 = MFMA16(ldcvt8(hb + (kk + 2) * 32), whf[kk + 2], c2);
          c3 = MFMA16(ldcvt8(hb + (kk + 3) * 32), whf[kk + 3], c3);
        }
      } else {
#pragma unroll
        for (int kk = 0; kk < 16; kk += 4) {
          c0 = MFMA16(LA(kk + 0), whf[kk + 0], c0);
          c1 = MFMA16(LA(kk + 1), whf[kk + 1], c1);
          c2 = MFMA16(LA(kk + 2), whf[kk + 2], c2);
          c3 = MFMA16(LA(kk + 3), whf[kk + 3], c3);
        }
      }
      f32x4 acc = (c0 + c1) + (c2 + c3);
      float hv0 = fmaxf(acc[0], 0.f), hv1 = fmaxf(acc[1], 0.f);
      float hv2 = fmaxf(acc[2], 0.f), hv3 = fmaxf(acc[3], 0.f);
      if (t == SEQ - 1) {  // h_final layer 1
        float* hfo = out + OUT0_ELEMS + (size_t)(NBAT + gb) * NH + jg;
        hfo[(size_t)(4 * kgrp + 0) * NH] = hv0;
        hfo[(size_t)(4 * kgrp + 1) * NH] = hv1;
        hfo[(size_t)(4 * kgrp + 2) * NH] = hv2;
        hfo[(size_t)(4 * kgrp + 3) * NH] = hv3;
      }
      {  // h1[t] -> ring1 slot t&1
        char* rb = ring1 + (size_t)(t & 1) * 16384 + jg * 2;
        st_sc_u16(rb + (4 * kgrp + 0) * 1024, h2b(hv0));
        st_sc_u16(rb + (4 * kgrp + 1) * 1024, h2b(hv1));
        st_sc_u16(rb + (4 * kgrp + 2) * 1024, h2b(hv2));
        st_sc_u16(rb + (4 * kgrp + 3) * 1024, h2b(hv3));
      }
      WAIT_VM0();
      if (lane == 0) st_sc_u32(fb + 128 + fq4, (u32)(t + 1));
      {  // final output out[t][b][j]: after the tag, drained next staging wait
        float* ob = out + ((size_t)t * NBAT + gb) * NH + jg;
        ob[(size_t)(4 * kgrp + 0) * NH] = hv0;
        ob[(size_t)(4 * kgrp + 1) * NH] = hv1;
        ob[(size_t)(4 * kgrp + 2) * NH] = hv2;
        ob[(size_t)(4 * kgrp + 3) * NH] = hv3;
      }
      if (t < SEQ - 1) {  // shadow: xacc(t+1) = bias + Wi1 @ h0[t+1] (from SB)
        xc0 = bias4; xc1 = zero4; xc2 = zero4; xc3 = zero4;
#pragma unroll
        for (int kk = 0; kk < 16; kk += 4) {
          xc0 = MFMA16(LB(kk + 0), wif[kk + 0], xc0);
          xc1 = MFMA16(LB(kk + 1), wif[kk + 1], xc1);
          xc2 = MFMA16(LB(kk + 2), wif[kk + 2], xc2);
          xc3 = MFMA16(LB(kk + 3), wif[kk + 3], xc3);
        }
      }
    }
  }
#undef LA
#undef LB
#undef SPIN_OR_DIE
}

extern "C" void kernel_launch(void* const* d_in, const int* in_sizes, int n_in,
                              void* d_out, int out_size, void* d_ws, size_t ws_size,
                              hipStream_t stream) {
  (void)in_sizes; (void)n_in; (void)out_size; (void)ws_size;
  const float* x = (const float*)d_in[0];
  const float* hx = (const float*)d_in[1];
  const float* w_ih = (const float*)d_in[2];
  const float* w_hh = (const float*)d_in[3];
  const float* b_ih = (const float*)d_in[4];
  const float* b_hh = (const float*)d_in[5];
  float* out = (float*)d_out;
  char* ws = (char*)d_ws;

  // zero gab + tags (agent-coherent); rings are flag-gated
  (void)hipMemsetAsync(d_ws, 0, 8192, stream);
  pre0_gemm<<<dim3(2048), dim3(256), 0, stream>>>(x, w_ih, b_ih, b_hh, out);
  rnn_pers<<<dim3(64), dim3(256), 0, stream>>>(x, hx, w_ih, w_hh, b_ih, b_hh, out, ws);
}

// Round 13
// 6555.100 us; speedup vs baseline: 1.1673x; 1.1673x over previous
//
#include <hip/hip_runtime.h>

typedef _Float16 f16;
typedef _Float16 f16x8 __attribute__((ext_vector_type(8)));
typedef float f32x4 __attribute__((ext_vector_type(4)));
typedef unsigned int u32;
typedef u32 u32x4 __attribute__((ext_vector_type(4)));

#define SEQ 2048
#define NBAT 64
#define NH 512
#define OUT0_ELEMS (SEQ * NBAT * NH)
#define TSLICE (NBAT * NH)  // 32768 f32 per t-slice

#define AGENT __HIP_MEMORY_SCOPE_AGENT
#define RLX __ATOMIC_RELAXED

// ws layout (memset [0,8192) each launch; rings are flag-gated, not cleared):
//   [0,64)        gab
//   64+c*512      tags0[32] (8B stride) @+0, tags1[32] @+256   (c = 0..3)
//   8192          ring0: + c*131072, 8 slots x 16384B ([16 b][512 f] f16)
//   532480        ring1: + c*32768,  2 slots x 16384B
#define WS_FLAGS 64
#define WS_RING0 8192
#define WS_RING1 (8192 + 4 * 131072)

#define MFMA16(a, b, c) __builtin_amdgcn_mfma_f32_16x16x32_f16((a), (b), (c), 0, 0, 0)

#define WAIT_VM0()                                   \
  do {                                               \
    asm volatile("s_waitcnt vmcnt(0)" ::: "memory"); \
    __builtin_amdgcn_sched_barrier(0);               \
  } while (0)

// ---- agent-scope (R1/R4/R6/R8/R10-proven) memory ops: sc0 sc1 ----
__device__ __forceinline__ u32x4 ld_sc(const void* p) {
  u32x4 d;
  asm volatile("global_load_dwordx4 %0, %1, off sc0 sc1" : "=v"(d) : "v"(p) : "memory");
  return d;
}
__device__ __forceinline__ void st_sc_u32(void* p, u32 v) {
  asm volatile("global_store_dword %0, %1, off sc0 sc1" ::"v"(p), "v"(v) : "memory");
}
__device__ __forceinline__ void st_sc_u16(void* p, u32 v) {
  asm volatile("global_store_short %0, %1, off sc0 sc1" ::"v"(p), "v"(v) : "memory");
}
__device__ __forceinline__ u32 poll_sc(const void* p) {
  u32 d;
  asm volatile("global_load_dword %0, %1, off sc0 sc1\n\ts_waitcnt vmcnt(0)"
               : "=v"(d) : "v"(p) : "memory");
  return d;
}

__device__ __forceinline__ f16x8 cvt2(float4 a, float4 b) {
  f16x8 v;
  v[0] = (f16)a.x; v[1] = (f16)a.y; v[2] = (f16)a.z; v[3] = (f16)a.w;
  v[4] = (f16)b.x; v[5] = (f16)b.y; v[6] = (f16)b.z; v[7] = (f16)b.w;
  return v;
}
__device__ __forceinline__ f16x8 ldcvt8(const float* p) {
  float4 a = *(const float4*)p;
  float4 b = *(const float4*)(p + 4);
  return cvt2(a, b);
}
__device__ __forceinline__ u32 h2b(float v) {
  union { f16 h[2]; u32 u; } x;
  x.u = 0;
  x.h[0] = (f16)v;
  return x.u;
}

// lanes<32 poll tags0[lane] >= tgtA ; lanes>=32 poll tags1[lane-32] >= tgtB
__device__ __forceinline__ bool spin2(const char* fb, u32 tgtA, u32 tgtB, u32* gab) {
  const int lane = threadIdx.x & 63;
  const char* p = fb + lane * 8;
  const u32 tgt = (lane < 32) ? tgtA : tgtB;
  int it = 0;
  for (;;) {
    u32 v = poll_sc(p);
    if (__all((int)(v >= tgt))) return true;
    if (((++it) & 63) == 0) {
      if (__hip_atomic_load(gab, RLX, AGENT) || it > (1 << 20)) {
        __hip_atomic_store(gab, 1u, RLX, AGENT);
        return false;
      }
    }
  }
}

// ============ kernel 1: pre0[t] = b_ih0 + b_hh0 + Wi0 @ x[t], D-frag layout ===
// grid 1024 = c(4) x r(8) x ch(32); block 256. 16 batches per cluster.
__global__ __launch_bounds__(256) void pre0_gemm(
    const float* __restrict__ x, const float* __restrict__ w_ih,
    const float* __restrict__ b_ih, const float* __restrict__ b_hh,
    float* __restrict__ out) {
  __shared__ __align__(16) char XT[16384];  // x[t] 16-batch slice, f16, swizzled
  const int tid = threadIdx.x;
  const int lane = tid & 63;
  const int wv = tid >> 6;
  const int bid = blockIdx.x;
  const int c = bid >> 8;
  const int r = (bid >> 5) & 7;
  const int ch = bid & 31;
  const int gb = c * 16;
  const int mrow = lane & 15;
  const int kgrp = lane >> 4;
  const int jl = wv * 16 + mrow;
  const int jg = r * 64 + jl;
  const int rsw = (mrow & 7) << 4;

  f16x8 wif[16];
  {
    const float* s1 = w_ih + (size_t)jg * NH + kgrp * 8;
#pragma unroll
    for (int kk = 0; kk < 16; ++kk) wif[kk] = ldcvt8(s1 + kk * 32);
  }
  const float bias = b_ih[jg] + b_hh[jg];
  const f32x4 bias4 = {bias, bias, bias, bias};
  const f32x4 zero4 = {0.f, 0.f, 0.f, 0.f};

  const int sb = tid >> 4;         // staged batch row 0..15
  const int sk = (tid & 15) * 32;  // staged f32 start (32 per thread)
  const int ssw = (sb & 7) << 4;

#define XA(kk) (*(const f16x8*)(XT + mrow * 1024 + ((((kk) * 64) + kgrp * 16) ^ rsw)))

  for (int ti = 0; ti < 64; ++ti) {
    const int t = ch * 64 + ti;
    {  // stage x[t] 16-batch slice -> f16 LDS (swizzled)
      const float* sp = x + ((size_t)t * NBAT + gb + sb) * NH + sk;
      float4 a0 = *(const float4*)(sp + 0),  a1 = *(const float4*)(sp + 4);
      float4 a2 = *(const float4*)(sp + 8),  a3 = *(const float4*)(sp + 12);
      float4 a4 = *(const float4*)(sp + 16), a5 = *(const float4*)(sp + 20);
      float4 a6 = *(const float4*)(sp + 24), a7 = *(const float4*)(sp + 28);
      union { f16x8 h; u32x4 u; } v0, v1, v2, v3;
      v0.h = cvt2(a0, a1); v1.h = cvt2(a2, a3);
      v2.h = cvt2(a4, a5); v3.h = cvt2(a6, a7);
      char* d = XT + sb * 1024;
      *(u32x4*)(d + ((sk * 2 + 0) ^ ssw)) = v0.u;
      *(u32x4*)(d + ((sk * 2 + 16) ^ ssw)) = v1.u;
      *(u32x4*)(d + ((sk * 2 + 32) ^ ssw)) = v2.u;
      *(u32x4*)(d + ((sk * 2 + 48) ^ ssw)) = v3.u;
    }
    __syncthreads();
    f32x4 c0 = bias4, c1 = zero4, c2 = zero4, c3 = zero4;
#pragma unroll
    for (int kk = 0; kk < 16; kk += 4) {
      c0 = MFMA16(XA(kk + 0), wif[kk + 0], c0);
      c1 = MFMA16(XA(kk + 1), wif[kk + 1], c1);
      c2 = MFMA16(XA(kk + 2), wif[kk + 2], c2);
      c3 = MFMA16(XA(kk + 3), wif[kk + 3], c3);
    }
    f32x4 acc = (c0 + c1) + (c2 + c3);
    const int fi = ((c * 8 + r) * 4 + wv) * 64 + kgrp * 16 + mrow;
    *(f32x4*)(out + (size_t)t * TSLICE + (size_t)fi * 4) = acc;
    __syncthreads();
  }
#undef XA
}

// ===== kernel 2: persistent recurrence (R8 protocol + cooperative staging) ===
// grid = 64 WGs x 256 thr. c = bid>>4 (16 batches), layer = (bid>>3)&1, r = bid&7.
__global__ __launch_bounds__(256, 1) void rnn_pers(
    const float* __restrict__ x, const float* __restrict__ hx,
    const float* __restrict__ w_ih, const float* __restrict__ w_hh,
    const float* __restrict__ b_ih, const float* __restrict__ b_hh,
    float* __restrict__ out, char* __restrict__ ws) {
  __shared__ __align__(16) char SA[16384];
  __shared__ __align__(16) char SB[16384];
  __shared__ u32 okf;

  const int tid = threadIdx.x;
  const int lane = tid & 63;
  const int wv = tid >> 6;
  const int bid = blockIdx.x;
  const int c = bid >> 4;
  const int layer = (bid >> 3) & 1;
  const int r = bid & 7;

  const int mrow = lane & 15;     // A-row = batch 0..15 (all real)
  const int kgrp = lane >> 4;     // 0..3
  const int jl = wv * 16 + mrow;  // feature within 64-slice
  const int jg = r * 64 + jl;     // global feature
  const int gb = c * 16;
  const int fq = (r * 4 + wv) * 8;
  const int rsw = (mrow & 7) << 4;

  // cooperative staging geometry: thread stages 64B of the 16KB slot:
  // src bytes tid*64 .. +63 ; LDS row ro=tid>>4, cols ((tid&15)*64+j*16)^((ro&7)<<4)
  const int q64 = tid * 64;
  const int ro = tid >> 4;
  const int wb = ro * 1024;
  const int wsw = (ro & 7) << 4;
  const int wc0 = wb + ((((tid & 15) * 64) + 0) ^ wsw);
  const int wc1 = wb + ((((tid & 15) * 64) + 16) ^ wsw);
  const int wc2 = wb + ((((tid & 15) * 64) + 32) ^ wsw);
  const int wc3 = wb + ((((tid & 15) * 64) + 48) ^ wsw);

  u32* gab = (u32*)ws;
  char* fb = ws + WS_FLAGS + c * 512;
  char* ring0 = ws + WS_RING0 + (size_t)c * 131072;
  char* ring1 = ws + WS_RING1 + (size_t)c * 32768;

  // wv0 polls; okf broadcasts; abort returns the WHOLE WG together (barrier-safe)
#define SPIN_OR_DIE(tgA, tgB)                  \
  do {                                         \
    if (wv == 0) {                             \
      bool ok_ = spin2(fb, (tgA), (tgB), gab); \
      if (lane == 0) okf = ok_ ? 1u : 2u;      \
    }                                          \
    __syncthreads();                           \
    if (okf != 1u) return;                     \
  } while (0)

#define LA(kk) (*(const f16x8*)(SA + mrow * 1024 + ((kgrp * 16 + (kk) * 64) ^ rsw)))
#define LB(kk) (*(const f16x8*)(SB + mrow * 1024 + ((kgrp * 16 + (kk) * 64) ^ rsw)))

  f16x8 whf[16];
  {
    const float* s2 = w_hh + ((size_t)layer * NH + jg) * NH + kgrp * 8;
#pragma unroll
    for (int kk = 0; kk < 16; ++kk) whf[kk] = ldcvt8(s2 + kk * 32);
  }
  const f32x4 zero4 = {0.f, 0.f, 0.f, 0.f};

  if (layer == 0) {
    // ============================ LAYER 0 ============================
    const float* pf =
        out + ((size_t)((c * 8 + r) * 4 + wv) * 64 + kgrp * 16 + mrow) * 4;
    f32x4 xpA = *(const f32x4*)pf;                          // pre0[0]
    f32x4 xpB = *(const f32x4*)(pf + (size_t)TSLICE);       // pre0[1]
    f32x4 xpC = *(const f32x4*)(pf + (size_t)2 * TSLICE);   // pre0[2]
    for (int t = 0; t < SEQ; ++t) {
      f32x4 c0 = xpA, c1 = zero4, c2 = zero4, c3 = zero4;
      if (t == 0) {
        const float* hb = hx + (size_t)(gb + mrow) * NH + kgrp * 8;
#pragma unroll
        for (int kk = 0; kk < 16; kk += 4) {
          c0 = MFMA16(ldcvt8(hb + (kk + 0) * 32), whf[kk + 0], c0);
          c1 = MFMA16(ldcvt8(hb + (kk + 1) * 32), whf[kk + 1], c1);
          c2 = MFMA16(ldcvt8(hb + (kk + 2) * 32), whf[kk + 2], c2);
          c3 = MFMA16(ldcvt8(hb + (kk + 3) * 32), whf[kk + 3], c3);
        }
      } else {
        // tags0>=t : h0[t-1] ready ; tags1>=t-7 : ring0 slot t&7 reusable
        SPIN_OR_DIE((u32)t, (t >= 7) ? (u32)(t - 7) : 0u);
        {  // cooperative stage: ring0 slot (t-1)&7 -> SA (16KB once per WG)
          const char* sp = ring0 + (size_t)((t - 1) & 7) * 16384 + q64;
          u32x4 s0 = ld_sc(sp);
          u32x4 s1 = ld_sc(sp + 16);
          u32x4 s2 = ld_sc(sp + 32);
          u32x4 s3 = ld_sc(sp + 48);
          WAIT_VM0();  // asm loads MUST drain before LDS writes
          *(u32x4*)(SA + wc0) = s0;
          *(u32x4*)(SA + wc1) = s1;
          *(u32x4*)(SA + wc2) = s2;
          *(u32x4*)(SA + wc3) = s3;
        }
        __syncthreads();
#pragma unroll
        for (int kk = 0; kk < 16; kk += 4) {
          c0 = MFMA16(LA(kk + 0), whf[kk + 0], c0);
          c1 = MFMA16(LA(kk + 1), whf[kk + 1], c1);
          c2 = MFMA16(LA(kk + 2), whf[kk + 2], c2);
          c3 = MFMA16(LA(kk + 3), whf[kk + 3], c3);
        }
      }
      f32x4 acc = (c0 + c1) + (c2 + c3);
      float hv0 = fmaxf(acc[0], 0.f), hv1 = fmaxf(acc[1], 0.f);
      float hv2 = fmaxf(acc[2], 0.f), hv3 = fmaxf(acc[3], 0.f);
      if (t == SEQ - 1) {  // h_final layer 0 (16 real batches)
        float* hfo = out + OUT0_ELEMS + (size_t)gb * NH + jg;
        hfo[(size_t)(4 * kgrp + 0) * NH] = hv0;
        hfo[(size_t)(4 * kgrp + 1) * NH] = hv1;
        hfo[(size_t)(4 * kgrp + 2) * NH] = hv2;
        hfo[(size_t)(4 * kgrp + 3) * NH] = hv3;
      }
      {  // h0[t] -> ring0 slot t&7 (batch 4*kgrp+i, feature jg)
        char* rb = ring0 + (size_t)(t & 7) * 16384 + jg * 2;
        st_sc_u16(rb + (4 * kgrp + 0) * 1024, h2b(hv0));
        st_sc_u16(rb + (4 * kgrp + 1) * 1024, h2b(hv1));
        st_sc_u16(rb + (4 * kgrp + 2) * 1024, h2b(hv2));
        st_sc_u16(rb + (4 * kgrp + 3) * 1024, h2b(hv3));
      }
      WAIT_VM0();
      if (lane == 0) st_sc_u32(fb + fq, (u32)(t + 1));
      xpA = xpB;  // pre0[t+3] prefetch: issued here, drained by next staging wait
      xpB = xpC;
      if (t + 3 < SEQ) xpC = *(const f32x4*)(pf + (size_t)(t + 3) * TSLICE);
    }
  } else {
    // ============================ LAYER 1 ============================
    f16x8 wif[16];
    {
      const float* s1 = w_ih + ((size_t)NH + jg) * NH + kgrp * 8;
#pragma unroll
      for (int kk = 0; kk < 16; ++kk) wif[kk] = ldcvt8(s1 + kk * 32);
    }
    const float bias = b_ih[NH + jg] + b_hh[NH + jg];
    const f32x4 bias4 = {bias, bias, bias, bias};
    f32x4 xc0, xc1, xc2, xc3;
    // prologue: xacc = bias + Wi1 @ h0[0]
    SPIN_OR_DIE(1u, 0u);
    {  // stage ring0 slot 0 -> SB
      const char* sp = ring0 + q64;
      u32x4 s0 = ld_sc(sp);
      u32x4 s1 = ld_sc(sp + 16);
      u32x4 s2 = ld_sc(sp + 32);
      u32x4 s3 = ld_sc(sp + 48);
      WAIT_VM0();
      *(u32x4*)(SB + wc0) = s0;
      *(u32x4*)(SB + wc1) = s1;
      *(u32x4*)(SB + wc2) = s2;
      *(u32x4*)(SB + wc3) = s3;
    }
    __syncthreads();
    xc0 = bias4; xc1 = zero4; xc2 = zero4; xc3 = zero4;
#pragma unroll
    for (int kk = 0; kk < 16; kk += 4) {
      xc0 = MFMA16(LB(kk + 0), wif[kk + 0], xc0);
      xc1 = MFMA16(LB(kk + 1), wif[kk + 1], xc1);
      xc2 = MFMA16(LB(kk + 2), wif[kk + 2], xc2);
      xc3 = MFMA16(LB(kk + 3), wif[kk + 3], xc3);
    }
    for (int t = 0; t < SEQ; ++t) {
      // tags0>=t+2 : h0[t+1] ready ; tags1>=t : h1[t-1] ready
      u32 tgtA = (t < SEQ - 1) ? (u32)(t + 2) : (u32)SEQ;
      SPIN_OR_DIE(tgtA, (u32)t);
      {  // cooperative stage: SA <- ring1 slot (t-1)&1 ; SB <- ring0 slot (t+1)&7
        u32x4 a0, a1, a2, a3, b0, b1, b2, b3;
        const bool doA = (t >= 1), doB = (t < SEQ - 1);
        if (doA) {
          const char* sp = ring1 + (size_t)((t - 1) & 1) * 16384 + q64;
          a0 = ld_sc(sp); a1 = ld_sc(sp + 16); a2 = ld_sc(sp + 32); a3 = ld_sc(sp + 48);
        }
        if (doB) {
          const char* sp = ring0 + (size_t)((t + 1) & 7) * 16384 + q64;
          b0 = ld_sc(sp); b1 = ld_sc(sp + 16); b2 = ld_sc(sp + 32); b3 = ld_sc(sp + 48);
        }
        WAIT_VM0();  // drain ALL asm loads before LDS writes
        if (doA) {
          *(u32x4*)(SA + wc0) = a0; *(u32x4*)(SA + wc1) = a1;
          *(u32x4*)(SA + wc2) = a2; *(u32x4*)(SA + wc3) = a3;
        }
        if (doB) {
          *(u32x4*)(SB + wc0) = b0; *(u32x4*)(SB + wc1) = b1;
          *(u32x4*)(SB + wc2) = b2; *(u32x4*)(SB + wc3) = b3;
        }
      }
      __syncthreads();
      f32x4 c0 = xc0, c1 = xc1, c2 = xc2, c3 = xc3;
      if (t == 0) {
        const float* hb = hx + (size_t)(NBAT + gb + mrow) * NH + kgrp * 8;
#pragma unroll
        for (int kk = 0; kk < 16; kk += 4) {
          c0 = MFMA16(ldcvt8(hb + (kk + 0) * 32), whf[kk + 0], c0);
          c1 = MFMA16(ldcvt8(hb + (kk + 1) * 32), whf[kk + 1], c1);
          c2 = MFMA16(ldcvt8(hb + (kk + 2) * 32), whf[kk + 2], c2);
          c3 = MFMA16(ldcvt8(hb + (kk + 3) * 32), whf[kk + 3], c3);
        }
      } else {
#pragma unroll
        for (int kk = 0; kk < 16; kk += 4) {
          c0 = MFMA16(LA(kk + 0), whf[kk + 0], c0);
          c1 = MFMA16(LA(kk + 1), whf[kk + 1], c1);
          c2 = MFMA16(LA(kk + 2), whf[kk + 2], c2);
          c3 = MFMA16(LA(kk + 3), whf[kk + 3], c3);
        }
      }
      f32x4 acc = (c0 + c1) + (c2 + c3);
      float hv0 = fmaxf(acc[0], 0.f), hv1 = fmaxf(acc[1], 0.f);
      float hv2 = fmaxf(acc[2], 0.f), hv3 = fmaxf(acc[3], 0.f);
      if (t == SEQ - 1) {  // h_final layer 1
        float* hfo = out + OUT0_ELEMS + (size_t)(NBAT + gb) * NH + jg;
        hfo[(size_t)(4 * kgrp + 0) * NH] = hv0;
        hfo[(size_t)(4 * kgrp + 1) * NH] = hv1;
        hfo[(size_t)(4 * kgrp + 2) * NH] = hv2;
        hfo[(size_t)(4 * kgrp + 3) * NH] = hv3;
      }
      {  // h1[t] -> ring1 slot t&1
        char* rb = ring1 + (size_t)(t & 1) * 16384 + jg * 2;
        st_sc_u16(rb + (4 * kgrp + 0) * 1024, h2b(hv0));
        st_sc_u16(rb + (4 * kgrp + 1) * 1024, h2b(hv1));
        st_sc_u16(rb + (4 * kgrp + 2) * 1024, h2b(hv2));
        st_sc_u16(rb + (4 * kgrp + 3) * 1024, h2b(hv3));
      }
      WAIT_VM0();
      if (lane == 0) st_sc_u32(fb + 256 + fq, (u32)(t + 1));
      {  // final output out[t][b][j]: after the tag, drained next staging wait
        float* ob = out + ((size_t)t * NBAT + gb) * NH + jg;
        ob[(size_t)(4 * kgrp + 0) * NH] = hv0;
        ob[(size_t)(4 * kgrp + 1) * NH] = hv1;
        ob[(size_t)(4 * kgrp + 2) * NH] = hv2;
        ob[(size_t)(4 * kgrp + 3) * NH] = hv3;
      }
      if (t < SEQ - 1) {  // shadow: xacc(t+1) = bias + Wi1 @ h0[t+1] (from SB)
        xc0 = bias4; xc1 = zero4; xc2 = zero4; xc3 = zero4;
#pragma unroll
        for (int kk = 0; kk < 16; kk += 4) {
          xc0 = MFMA16(LB(kk + 0), wif[kk + 0], xc0);
          xc1 = MFMA16(LB(kk + 1), wif[kk + 1], xc1);
          xc2 = MFMA16(LB(kk + 2), wif[kk + 2], xc2);
          xc3 = MFMA16(LB(kk + 3), wif[kk + 3], xc3);
        }
      }
    }
  }
#undef LA
#undef LB
#undef SPIN_OR_DIE
}

extern "C" void kernel_launch(void* const* d_in, const int* in_sizes, int n_in,
                              void* d_out, int out_size, void* d_ws, size_t ws_size,
                              hipStream_t stream) {
  (void)in_sizes; (void)n_in; (void)out_size; (void)ws_size;
  const float* x = (const float*)d_in[0];
  const float* hx = (const float*)d_in[1];
  const float* w_ih = (const float*)d_in[2];
  const float* w_hh = (const float*)d_in[3];
  const float* b_ih = (const float*)d_in[4];
  const float* b_hh = (const float*)d_in[5];
  float* out = (float*)d_out;
  char* ws = (char*)d_ws;

  // zero gab + tags (agent-coherent); rings are flag-gated
  (void)hipMemsetAsync(d_ws, 0, 8192, stream);
  pre0_gemm<<<dim3(1024), dim3(256), 0, stream>>>(x, w_ih, b_ih, b_hh, out);
  rnn_pers<<<dim3(64), dim3(256), 0, stream>>>(x, hx, w_ih, w_hh, b_ih, b_hh, out, ws);
}